// Round 29
// baseline (177.230 us; speedup 1.0000x reference)
//
#include <hip/hip_runtime.h>

// Problem constants
#define NDRUG 50000
#define NDIS  50000
#define RR    5
#define FF    128
#define EFFD  128
#define OUTD  64
#define EE    400000
#define NCOL  (RR * OUTD)        // 320 columns in fused OUTPUT layout [n][r*64+o]
#define NEDGE (RR * EE)          // 2,000,000 edges per direction

#define NROWP 50016              // padded rows per rating region (rows 50000..50015 are ZERO)

// Two-level bucket sort
#define NBKT    196              // coarse buckets per (dir,r): dst>>8 (50000/256)
#define CAP     4096             // slot capacity per bucket
#define NGB     (2 * RR * NBKT)  // 1960 global buckets

#define NCHUNKE 128              // edge chunks per r (both dirs handled per block)
#define CHUNKE  (EE / NCHUNKE)   // 3125 edges per chunk: run/bucket ~16 = one 64B line

// merged part+gemm dispatch geometry (gemm: 256 rows/block, 4 row-tiles/wave)
#define PART_BLOCKS (NCHUNKE * RR)            // 640
#define GEMM_RB     ((NDRUG + 255) / 256)     // 196 row-blocks
#define GEMM_BLOCKS (GEMM_RB * 4)             // x2 col-half x2 side = 784
#define PG_BLOCKS   (PART_BLOCKS + GEMM_BLOCKS)

typedef unsigned short ushort_t;
typedef unsigned int uint_t;
typedef short short8 __attribute__((ext_vector_type(8)));
typedef float f32x4 __attribute__((ext_vector_type(4)));
typedef float f32x2 __attribute__((ext_vector_type(2)));

// f32 -> bf16 round-to-nearest-even
static __device__ __forceinline__ ushort_t f2bf(float f) {
    uint_t u = __float_as_uint(f);
    uint_t r = (u + 0x7FFFu + ((u >> 16) & 1u)) >> 16;
    return (ushort_t)r;
}

// ---------------------------------------------------------------------------
// Kernel A: Mt[col][f] = bf16( sum_e (att[r,0]*basis[0,f,e]+att[r,1]*basis[1,f,e]) * fc_w[e,o] )
// ---------------------------------------------------------------------------
__global__ __launch_bounds__(256) void k_make_M(const float* __restrict__ att,
                                                const float* __restrict__ basis,
                                                const float* __restrict__ fcw,
                                                ushort_t* __restrict__ Mt) {
    int tid = blockIdx.x * 256 + threadIdx.x;
    if (tid >= RR * FF * OUTD) return;
    int r = tid / (FF * OUTD);
    int rem = tid - r * FF * OUTD;
    int f = rem >> 6;
    int o = rem & 63;
    float a0 = att[r * 2 + 0], a1 = att[r * 2 + 1];
    const float* b0 = basis + f * EFFD;
    const float* b1 = basis + FF * EFFD + f * EFFD;
    float acc = 0.f;
#pragma unroll 4
    for (int e = 0; e < EFFD; ++e) {
        float w = a0 * b0[e] + a1 * b1[e];
        acc += w * fcw[e * OUTD + o];
    }
    Mt[(size_t)(r * OUTD + o) * FF + f] = f2bf(acc);
}

// ---------------------------------------------------------------------------
// Merged Pass 1: part-blocks with LDS staging (dense-in-time bucket runs,
// 4 blocks/CU concurrency ceiling); gemm-blocks: 256 rows/block, FOUR
// row-tiles per wave sharing one Mt ping-pong pipeline (Mt load stream
// amortized over 4x rows), feat + Mt direct from global, no LDS.
// ---------------------------------------------------------------------------
__global__ __launch_bounds__(256, 4) void k_pg(const int* __restrict__ ed,
                                               const int* __restrict__ ei,
                                               int* __restrict__ tails,
                                               uint_t* __restrict__ coarse,
                                               const float* __restrict__ featA,
                                               const float* __restrict__ cjA,
                                               const float* __restrict__ featB,
                                               const float* __restrict__ cjB,
                                               const ushort_t* __restrict__ Mt,
                                               ushort_t* __restrict__ gA,
                                               ushort_t* __restrict__ gB) {
    __shared__ uint_t stage0[CHUNKE];
    __shared__ uint_t stage1[CHUNKE];
    __shared__ int cnt[2 * NBKT];
    __shared__ int cur[2 * NBKT];
    __shared__ int gpos[2 * NBKT];

    const int bid = blockIdx.x;
    const int t = threadIdx.x;

    if (bid < PART_BLOCKS) {
        // blocks 0..9: zero the pad rows (rows 50000..50015) of one region
        if (bid < 2 * RR) {
            ushort_t* garr = (bid & 1) ? gB : gA;
            int r = bid >> 1;
            uint_t* z = (uint_t*)(garr + ((size_t)r * NROWP + NDRUG) * OUTD);
            for (int i = t; i < 512; i += 256) z[i] = 0u;
        }

        // ---------------- coarse partition (both dirs per block) -----------
        int chunk = bid & (NCHUNKE - 1);
        int r = bid >> 7;
        const int* A = ed + (size_t)r * EE;   // drug endpoints
        const int* B = ei + (size_t)r * EE;   // disease endpoints
        int* tl0 = tails + (0 * RR + r) * NBKT;
        int* tl1 = tails + (1 * RR + r) * NBKT;
        uint_t* cb0 = coarse + (size_t)(0 * RR + r) * NBKT * CAP;
        uint_t* cb1 = coarse + (size_t)(1 * RR + r) * NBKT * CAP;

        for (int u = t; u < 2 * NBKT; u += 256) { cnt[u] = 0; cur[u] = 0; }
        __syncthreads();

        int e0 = chunk * CHUNKE;
        for (int i = t; i < CHUNKE; i += 256) {
            int a = __builtin_nontemporal_load(A + e0 + i);
            int b = __builtin_nontemporal_load(B + e0 + i);
            stage0[i] = ((uint_t)(b >> 8) << 24) | ((uint_t)(b & 255) << 16) | (uint_t)(ushort_t)a;
            stage1[i] = ((uint_t)(a >> 8) << 24) | ((uint_t)(a & 255) << 16) | (uint_t)(ushort_t)b;
            atomicAdd(&cnt[b >> 8], 1);
            atomicAdd(&cnt[NBKT + (a >> 8)], 1);
        }
        __syncthreads();

        for (int u = t; u < 2 * NBKT; u += 256) {
            int* tl = (u < NBKT) ? tl0 : tl1;
            int bb = (u < NBKT) ? u : u - NBKT;
            gpos[u] = atomicAdd(&tl[bb], cnt[u]);
        }
        __syncthreads();

        for (int i = t; i < CHUNKE; i += 256) {
            uint_t e = stage0[i];
            int b = e >> 24;
            int q = atomicAdd(&cur[b], 1);
            int idx = gpos[b] + q;
            if (idx < CAP)
                cb0[(size_t)b * CAP + idx] = e & 0x00FFFFFFu;
        }
        for (int i = t; i < CHUNKE; i += 256) {
            uint_t e = stage1[i];
            int b = e >> 24;
            int q = atomicAdd(&cur[NBKT + b], 1);
            int idx = gpos[NBKT + b] + q;
            if (idx < CAP)
                cb1[(size_t)b * CAP + idx] = e & 0x00FFFFFFu;
        }
        return;
    }

    // ---------------- MFMA transform g[r][n][o], 256 rows/block, no LDS -----
    int gid = bid - PART_BLOCKS;
    int bx = gid % GEMM_RB;
    int qq = gid / GEMM_RB;          // 0..3
    int by = qq & 1;                 // col-half
    int bz = qq >> 1;                // side

    const float* feat; const float* cj; ushort_t* g;
    if (bz == 0) { feat = featA; cj = cjA; g = gA; }
    else         { feat = featB; cj = cjB; g = gB; }

    const int row0 = bx * 256;
    const int ch0  = by * 160;

    const int w = t >> 6;
    const int l = t & 63;
    const int lr = l & 15;
    const int lg = l >> 4;

    int rows[4];
    float cjv[4];
    const float* fp[4];
#pragma unroll
    for (int m = 0; m < 4; ++m) {
        rows[m] = row0 + m * 64 + w * 16 + lr;
        int rc = rows[m] < NDRUG ? rows[m] : NDRUG - 1;
        cjv[m] = (rows[m] < NDRUG) ? cj[rows[m]] : 0.f;
        fp[m] = feat + (size_t)rc * FF;
    }

    // feat fragments direct from global, f32 -> bf16 in registers (4 row-tiles)
    short8 ff[4][4];
#pragma unroll
    for (int m = 0; m < 4; ++m) {
#pragma unroll
        for (int ks = 0; ks < 4; ++ks) {
            const float* p = fp[m] + ks * 32 + lg * 8;
            float4 a0 = *(const float4*)p;
            float4 a1 = *(const float4*)(p + 4);
            short8 fa;
            fa[0] = (short)f2bf(a0.x); fa[1] = (short)f2bf(a0.y);
            fa[2] = (short)f2bf(a0.z); fa[3] = (short)f2bf(a0.w);
            fa[4] = (short)f2bf(a1.x); fa[5] = (short)f2bf(a1.y);
            fa[6] = (short)f2bf(a1.z); fa[7] = (short)f2bf(a1.w);
            ff[m][ks] = fa;
        }
    }

    // Mt fragment (A-operand): lane holds Mt[ch0 + n*16 + lr][ks*32 + lg*8..]
    const ushort_t* mtb = Mt + (size_t)(ch0 + lr) * FF + lg * 8;

    // 2-deep software pipeline over n (static ping-pong indexing)
    short8 bf0[4], bf1[4];
#pragma unroll
    for (int ks = 0; ks < 4; ++ks)
        bf0[ks] = *(const short8*)(mtb + ks * 32);

#pragma unroll
    for (int n = 0; n < 10; ++n) {
        const bool even = (n & 1) == 0;
        if (n < 9) {
#pragma unroll
            for (int ks = 0; ks < 4; ++ks) {
                short8 nb = *(const short8*)(mtb + (size_t)(n + 1) * 16 * FF + ks * 32);
                if (even) bf1[ks] = nb; else bf0[ks] = nb;
            }
        }
        f32x4 c0 = {0.f, 0.f, 0.f, 0.f};
        f32x4 c1 = {0.f, 0.f, 0.f, 0.f};
        f32x4 c2 = {0.f, 0.f, 0.f, 0.f};
        f32x4 c3 = {0.f, 0.f, 0.f, 0.f};
#pragma unroll
        for (int ks = 0; ks < 4; ++ks) {
            short8 a = even ? bf0[ks] : bf1[ks];
            c0 = __builtin_amdgcn_mfma_f32_16x16x32_bf16(a, ff[0][ks], c0, 0, 0, 0);
            c1 = __builtin_amdgcn_mfma_f32_16x16x32_bf16(a, ff[1][ks], c1, 0, 0, 0);
            c2 = __builtin_amdgcn_mfma_f32_16x16x32_bf16(a, ff[2][ks], c2, 0, 0, 0);
            c3 = __builtin_amdgcn_mfma_f32_16x16x32_bf16(a, ff[3][ks], c3, 0, 0, 0);
        }
        // output: 4 consecutive cols = ch0 + n*16 + lg*4 + 0..3
        int col0 = ch0 + n * 16 + lg * 4;
        int rr = col0 >> 6;
        int oo = col0 & 63;
        ushort_t* gbase = g + (size_t)rr * NROWP * OUTD + oo;
#define STORE_ROW(M, C) \
        if (rows[M] < NDRUG) { \
            ushort4 pk; \
            pk.x = f2bf(C[0] * cjv[M]); \
            pk.y = f2bf(C[1] * cjv[M]); \
            pk.z = f2bf(C[2] * cjv[M]); \
            pk.w = f2bf(C[3] * cjv[M]); \
            *(ushort4*)&gbase[(size_t)rows[M] * OUTD] = pk; \
        }
        STORE_ROW(0, c0)
        STORE_ROW(1, c1)
        STORE_ROW(2, c2)
        STORE_ROW(3, c3)
#undef STORE_ROW
    }
}

// ---------------------------------------------------------------------------
// Pass 2 (merged fine-sort + aggregation): one block per coarse bucket.
// Wave-level scan (2 barriers); quarter-per-bin aggregation with 4-deep
// unrolled serial loop. XCD-contiguous bucket remap.
// ---------------------------------------------------------------------------
__global__ __launch_bounds__(256, 8) void k_fuse(const ushort_t* __restrict__ gd,
                                                 const ushort_t* __restrict__ gi,
                                                 const int* __restrict__ tails,
                                                 const uint_t* __restrict__ coarse,
                                                 const float* __restrict__ ci_drug,
                                                 const float* __restrict__ ci_dis,
                                                 const float* __restrict__ fcb,
                                                 float* __restrict__ out_drug,
                                                 float* __restrict__ out_dis) {
    int bid = blockIdx.x;
    int gb = (bid & 7) * (NGB / 8) + (bid >> 3);   // XCD-contiguous range
    int dir = gb / (RR * NBKT);
    int rem = gb - dir * (RR * NBKT);
    int r = rem / NBKT;
    int b = rem - r * NBKT;

    const ushort_t* g = dir ? gi : gd;
    const float* ci   = dir ? ci_drug : ci_dis;
    float* outp       = dir ? out_drug : out_dis;

    const uint_t* cb = coarse + (size_t)gb * CAP;
    int count = tails[gb]; if (count > CAP) count = CAP;

    __shared__ ushort_t lsorted[CAP];   // 8 KB
    __shared__ int hist[256];
    __shared__ int incl[256];           // inclusive scan
    __shared__ int cur[256];
    __shared__ int wsum[4];

    int t = threadIdx.x;
    const int w    = t >> 6;
    const int lane = t & 63;

    // register-stage the bucket: one NT read of coarse (uniform skip)
    uint_t ereg[16];
#pragma unroll
    for (int k = 0; k < 16; ++k) {
        if (k * 256 < count) {
            int i = k * 256 + t;
            ereg[k] = (i < count) ? __builtin_nontemporal_load(cb + i) : 0xFFFFFFFFu;
        } else {
            ereg[k] = 0xFFFFFFFFu;
        }
    }

    hist[t] = 0;
    __syncthreads();
#pragma unroll
    for (int k = 0; k < 16; ++k) {
        if (k * 256 < count) {
            if (ereg[k] != 0xFFFFFFFFu)
                atomicAdd(&hist[(ereg[k] >> 16) & 255], 1);
        }
    }
    __syncthreads();

    // wave-level inclusive scan of hist across the 256 threads
    int v = hist[t];
    int x = v;
#pragma unroll
    for (int off = 1; off < 64; off <<= 1) {
        int y = __shfl_up(x, off);
        if (lane >= off) x += y;
    }
    if (lane == 63) wsum[w] = x;
    __syncthreads();
    int base = 0;
#pragma unroll
    for (int i = 0; i < 4; ++i)
        if (i < w) base += wsum[i];
    int inc = x + base;
    incl[t] = inc;
    cur[t] = inc - v;                  // exclusive start
    __syncthreads();

#pragma unroll
    for (int k = 0; k < 16; ++k) {
        if (k * 256 < count) {
            uint_t e = ereg[k];
            if (e != 0xFFFFFFFFu) {
                int pos = atomicAdd(&cur[(e >> 16) & 255], 1);
                if (pos < CAP) lsorted[pos] = (ushort_t)e;
            }
        }
    }
    __syncthreads();

    // aggregation: wave w -> bins w*64..w*64+63, 4 at a time (1 per quarter)
    const int quarter = lane >> 4;
    const int q       = lane & 15;
    const ushort_t* grow = g + (size_t)r * NROWP * OUTD + q * 4;
    const float4 bb = *(const float4*)(fcb + q * 4);

    for (int ib = 0; ib < 16; ++ib) {
        int dstlow = w * 64 + ib * 4 + quarter;   // this quarter's bin
        int dst = b * 256 + dstlow;
        int start = dstlow ? incl[dstlow - 1] : 0;
        int end   = incl[dstlow];
        int len   = end - start;
        int lenm1 = len > 0 ? len - 1 : 0;
        if (start > CAP - 1) start = CAP - 1;     // empty-tail guard

        // loop bound = max over the 4 quarters in this wave
        int wm = len;
        wm = max(wm, __shfl_xor(wm, 16));
        wm = max(wm, __shfl_xor(wm, 32));

        f32x2 a01 = {0.f, 0.f}, a23 = {0.f, 0.f};
        for (int s = 0; s < wm; s += 4) {
            uint2 u[4];
#pragma unroll
            for (int k2 = 0; k2 < 4; ++k2) {
                int ss = s + k2;
                int so = ss < lenm1 ? ss : lenm1;
                int sj = (int)lsorted[start + so];
                u[k2] = *(const uint2*)(grow + (size_t)sj * OUTD);
            }
#pragma unroll
            for (int k2 = 0; k2 < 4; ++k2) {
                int ss = s + k2;
                bool act = ss < len;
                uint_t ux = act ? u[k2].x : 0u;
                uint_t uy = act ? u[k2].y : 0u;
                f32x2 p0 = { __uint_as_float(ux << 16), __uint_as_float(ux & 0xffff0000u) };
                f32x2 p1 = { __uint_as_float(uy << 16), __uint_as_float(uy & 0xffff0000u) };
                a01 += p0;
                a23 += p1;
            }
        }
        if (dst < NDIS) {
            float civ = ci[dst];
            f32x4 o;
            o.x = a01.x * civ + bb.x;
            o.y = a01.y * civ + bb.y;
            o.z = a23.x * civ + bb.z;
            o.w = a23.y * civ + bb.w;
            __builtin_nontemporal_store(o,
                (f32x4*)(outp + (size_t)dst * NCOL + r * OUTD + q * 4));
        }
    }
}

// ---------------------------------------------------------------------------
extern "C" void kernel_launch(void* const* d_in, const int* in_sizes, int n_in,
                              void* d_out, int out_size, void* d_ws, size_t ws_size,
                              hipStream_t stream) {
    const float* drug_feat = (const float*)d_in[0];
    const float* dis_feat  = (const float*)d_in[1];
    const float* cj_drug   = (const float*)d_in[2];
    const float* ci_drug   = (const float*)d_in[3];
    const float* cj_dis    = (const float*)d_in[4];
    const float* ci_dis    = (const float*)d_in[5];
    const float* att       = (const float*)d_in[6];
    const float* basis     = (const float*)d_in[7];
    const float* fcw       = (const float*)d_in[8];
    const float* fcb       = (const float*)d_in[9];
    const int*   edge_drug = (const int*)d_in[10];
    const int*   edge_dis  = (const int*)d_in[11];

    float* out      = (float*)d_out;
    float* out_drug = out;
    float* out_dis  = out + (size_t)NDRUG * NCOL;

    // Workspace layout (~96.3 MB):
    //   gd (bf16, [R][50016][64])  32,010,240 @ 0
    //   gi (bf16, [R][50016][64])  32,010,240 @ 32,010,240
    //   Mt (bf16)          163,840 @ 64,020,480
    //   tails (int)          7,840 @ 64,184,320
    //   coarse (u32)    32,112,640 @ 64,192,160
    char* ws = (char*)d_ws;
    ushort_t* gd      = (ushort_t*)ws;
    ushort_t* gi      = (ushort_t*)(ws + 32010240);
    ushort_t* Mtb     = (ushort_t*)(ws + 64020480);
    int*      tails   = (int*)(ws + 64184320);
    uint_t*   coarse  = (uint_t*)(ws + 64192160);

    // zero bucket tails
    hipMemsetAsync(tails, 0, NGB * sizeof(int), stream);

    // A: fused att*basis*fc_w -> Mt bf16 [320][128]
    k_make_M<<<dim3((RR * FF * OUTD + 255) / 256), 256, 0, stream>>>(att, basis, fcw, Mtb);

    // Merged: coarse partition + pad-row zeroing + MFMA transform (256 rows/blk)
    k_pg<<<dim3(PG_BLOCKS), 256, 0, stream>>>(edge_drug, edge_dis, tails, coarse,
                                              drug_feat, cj_drug, dis_feat, cj_dis,
                                              Mtb, gd, gi);

    // Merged fine-sort + quarter-per-bin aggregation + fused ci-scale + bias
    k_fuse<<<dim3(NGB), 256, 0, stream>>>(gd, gi, tails, coarse,
                                          ci_drug, ci_dis, fcb,
                                          out_drug, out_dis);
}

// Round 30
// 164.907 us; speedup vs baseline: 1.0747x; 1.0747x over previous
//
#include <hip/hip_runtime.h>

// Problem constants
#define NDRUG 50000
#define NDIS  50000
#define RR    5
#define FF    128
#define EFFD  128
#define OUTD  64
#define EE    400000
#define NCOL  (RR * OUTD)        // 320 columns in fused OUTPUT layout [n][r*64+o]
#define NEDGE (RR * EE)          // 2,000,000 edges per direction

#define NROWP 50016              // padded rows per rating region (rows 50000..50015 are ZERO)

// Two-level bucket sort
#define NBKT    196              // coarse buckets per (dir,r): dst>>8 (50000/256)
#define CAP     4096             // slot capacity per bucket
#define NGB     (2 * RR * NBKT)  // 1960 global buckets

#define NCHUNKE 128              // edge chunks per r (both dirs handled per block)
#define CHUNKE  (EE / NCHUNKE)   // 3125 edges per chunk: run/bucket ~16 = one 64B line

// merged part+gemm dispatch geometry (gemm: 128 rows/block, 2 row-tiles/wave)
#define PART_BLOCKS (NCHUNKE * RR)            // 640
#define GEMM_RB     ((NDRUG + 127) / 128)     // 391 row-blocks
#define GEMM_BLOCKS (GEMM_RB * 4)             // x2 col-half x2 side = 1564
#define PG_BLOCKS   (PART_BLOCKS + GEMM_BLOCKS)

typedef unsigned short ushort_t;
typedef unsigned int uint_t;
typedef short short8 __attribute__((ext_vector_type(8)));
typedef float f32x4 __attribute__((ext_vector_type(4)));
typedef float f32x2 __attribute__((ext_vector_type(2)));

// f32 -> bf16 round-to-nearest-even
static __device__ __forceinline__ ushort_t f2bf(float f) {
    uint_t u = __float_as_uint(f);
    uint_t r = (u + 0x7FFFu + ((u >> 16) & 1u)) >> 16;
    return (ushort_t)r;
}

// ---------------------------------------------------------------------------
// Kernel A: Mt[col][f] = bf16( sum_e (att[r,0]*basis[0,f,e]+att[r,1]*basis[1,f,e]) * fc_w[e,o] )
// ---------------------------------------------------------------------------
__global__ __launch_bounds__(256) void k_make_M(const float* __restrict__ att,
                                                const float* __restrict__ basis,
                                                const float* __restrict__ fcw,
                                                ushort_t* __restrict__ Mt) {
    int tid = blockIdx.x * 256 + threadIdx.x;
    if (tid >= RR * FF * OUTD) return;
    int r = tid / (FF * OUTD);
    int rem = tid - r * FF * OUTD;
    int f = rem >> 6;
    int o = rem & 63;
    float a0 = att[r * 2 + 0], a1 = att[r * 2 + 1];
    const float* b0 = basis + f * EFFD;
    const float* b1 = basis + FF * EFFD + f * EFFD;
    float acc = 0.f;
#pragma unroll 4
    for (int e = 0; e < EFFD; ++e) {
        float w = a0 * b0[e] + a1 * b1[e];
        acc += w * fcw[e * OUTD + o];
    }
    Mt[(size_t)(r * OUTD + o) * FF + f] = f2bf(acc);
}

// ---------------------------------------------------------------------------
// Merged Pass 1 (round-25/28 configuration, launch_bounds(256,4)): part-blocks
// use LDS staging so each bucket's global run (~16 entries = one 64B line)
// is written back-to-back at LOW concurrency (4 blocks/CU keeps tail lines
// completed before eviction); gemm-blocks: 128 rows/block, 2 row-tiles/wave,
// feat + Mt direct from global, no LDS for the gemm role.
// ---------------------------------------------------------------------------
__global__ __launch_bounds__(256, 4) void k_pg(const int* __restrict__ ed,
                                               const int* __restrict__ ei,
                                               int* __restrict__ tails,
                                               uint_t* __restrict__ coarse,
                                               const float* __restrict__ featA,
                                               const float* __restrict__ cjA,
                                               const float* __restrict__ featB,
                                               const float* __restrict__ cjB,
                                               const ushort_t* __restrict__ Mt,
                                               ushort_t* __restrict__ gA,
                                               ushort_t* __restrict__ gB) {
    __shared__ uint_t stage0[CHUNKE];
    __shared__ uint_t stage1[CHUNKE];
    __shared__ int cnt[2 * NBKT];
    __shared__ int cur[2 * NBKT];
    __shared__ int gpos[2 * NBKT];

    const int bid = blockIdx.x;
    const int t = threadIdx.x;

    if (bid < PART_BLOCKS) {
        // blocks 0..9: zero the pad rows (rows 50000..50015) of one region
        if (bid < 2 * RR) {
            ushort_t* garr = (bid & 1) ? gB : gA;
            int r = bid >> 1;
            uint_t* z = (uint_t*)(garr + ((size_t)r * NROWP + NDRUG) * OUTD);
            for (int i = t; i < 512; i += 256) z[i] = 0u;
        }

        // ---------------- coarse partition (both dirs per block) -----------
        int chunk = bid & (NCHUNKE - 1);
        int r = bid >> 7;
        const int* A = ed + (size_t)r * EE;   // drug endpoints
        const int* B = ei + (size_t)r * EE;   // disease endpoints
        int* tl0 = tails + (0 * RR + r) * NBKT;
        int* tl1 = tails + (1 * RR + r) * NBKT;
        uint_t* cb0 = coarse + (size_t)(0 * RR + r) * NBKT * CAP;
        uint_t* cb1 = coarse + (size_t)(1 * RR + r) * NBKT * CAP;

        for (int u = t; u < 2 * NBKT; u += 256) { cnt[u] = 0; cur[u] = 0; }
        __syncthreads();

        int e0 = chunk * CHUNKE;
        for (int i = t; i < CHUNKE; i += 256) {
            int a = __builtin_nontemporal_load(A + e0 + i);
            int b = __builtin_nontemporal_load(B + e0 + i);
            stage0[i] = ((uint_t)(b >> 8) << 24) | ((uint_t)(b & 255) << 16) | (uint_t)(ushort_t)a;
            stage1[i] = ((uint_t)(a >> 8) << 24) | ((uint_t)(a & 255) << 16) | (uint_t)(ushort_t)b;
            atomicAdd(&cnt[b >> 8], 1);
            atomicAdd(&cnt[NBKT + (a >> 8)], 1);
        }
        __syncthreads();

        for (int u = t; u < 2 * NBKT; u += 256) {
            int* tl = (u < NBKT) ? tl0 : tl1;
            int bb = (u < NBKT) ? u : u - NBKT;
            gpos[u] = atomicAdd(&tl[bb], cnt[u]);
        }
        __syncthreads();

        for (int i = t; i < CHUNKE; i += 256) {
            uint_t e = stage0[i];
            int b = e >> 24;
            int q = atomicAdd(&cur[b], 1);
            int idx = gpos[b] + q;
            if (idx < CAP)
                cb0[(size_t)b * CAP + idx] = e & 0x00FFFFFFu;
        }
        for (int i = t; i < CHUNKE; i += 256) {
            uint_t e = stage1[i];
            int b = e >> 24;
            int q = atomicAdd(&cur[NBKT + b], 1);
            int idx = gpos[NBKT + b] + q;
            if (idx < CAP)
                cb1[(size_t)b * CAP + idx] = e & 0x00FFFFFFu;
        }
        return;
    }

    // ---------------- MFMA transform g[r][n][o], 128 rows/block, no LDS -----
    int gid = bid - PART_BLOCKS;
    int bx = gid % GEMM_RB;
    int qq = gid / GEMM_RB;          // 0..3
    int by = qq & 1;                 // col-half
    int bz = qq >> 1;                // side

    const float* feat; const float* cj; ushort_t* g;
    if (bz == 0) { feat = featA; cj = cjA; g = gA; }
    else         { feat = featB; cj = cjB; g = gB; }

    const int row0 = bx * 128;
    const int ch0  = by * 160;

    const int w = t >> 6;
    const int l = t & 63;
    const int lr = l & 15;
    const int lg = l >> 4;

    const int rowA = row0 + w * 16 + lr;
    const int rowB = rowA + 64;
    const int rA = rowA < NDRUG ? rowA : NDRUG - 1;   // clamped (reads valid)
    const int rB = rowB < NDRUG ? rowB : NDRUG - 1;
    const float cjvA = (rowA < NDRUG) ? cj[rowA] : 0.f;
    const float cjvB = (rowB < NDRUG) ? cj[rowB] : 0.f;

    // feat fragments direct from global, f32 -> bf16 in registers
    short8 ffA[4], ffB[4];
#pragma unroll
    for (int ks = 0; ks < 4; ++ks) {
        const float* pA = feat + (size_t)rA * FF + ks * 32 + lg * 8;
        const float* pB = feat + (size_t)rB * FF + ks * 32 + lg * 8;
        float4 a0 = *(const float4*)pA;
        float4 a1 = *(const float4*)(pA + 4);
        float4 b0 = *(const float4*)pB;
        float4 b1 = *(const float4*)(pB + 4);
        short8 fa, fb;
        fa[0] = (short)f2bf(a0.x); fa[1] = (short)f2bf(a0.y);
        fa[2] = (short)f2bf(a0.z); fa[3] = (short)f2bf(a0.w);
        fa[4] = (short)f2bf(a1.x); fa[5] = (short)f2bf(a1.y);
        fa[6] = (short)f2bf(a1.z); fa[7] = (short)f2bf(a1.w);
        fb[0] = (short)f2bf(b0.x); fb[1] = (short)f2bf(b0.y);
        fb[2] = (short)f2bf(b0.z); fb[3] = (short)f2bf(b0.w);
        fb[4] = (short)f2bf(b1.x); fb[5] = (short)f2bf(b1.y);
        fb[6] = (short)f2bf(b1.z); fb[7] = (short)f2bf(b1.w);
        ffA[ks] = fa;
        ffB[ks] = fb;
    }

    // Mt fragment (A-operand): lane holds Mt[ch0 + n*16 + lr][ks*32 + lg*8..]
    const ushort_t* mtb = Mt + (size_t)(ch0 + lr) * FF + lg * 8;

    // 2-deep software pipeline over n (static ping-pong indexing)
    short8 bf0[4], bf1[4];
#pragma unroll
    for (int ks = 0; ks < 4; ++ks)
        bf0[ks] = *(const short8*)(mtb + ks * 32);

#pragma unroll
    for (int n = 0; n < 10; ++n) {
        const bool even = (n & 1) == 0;
        if (n < 9) {
#pragma unroll
            for (int ks = 0; ks < 4; ++ks) {
                short8 nb = *(const short8*)(mtb + (size_t)(n + 1) * 16 * FF + ks * 32);
                if (even) bf1[ks] = nb; else bf0[ks] = nb;
            }
        }
        f32x4 cA = {0.f, 0.f, 0.f, 0.f};
        f32x4 cB = {0.f, 0.f, 0.f, 0.f};
#pragma unroll
        for (int ks = 0; ks < 4; ++ks) {
            short8 a = even ? bf0[ks] : bf1[ks];
            cA = __builtin_amdgcn_mfma_f32_16x16x32_bf16(a, ffA[ks], cA, 0, 0, 0);
            cB = __builtin_amdgcn_mfma_f32_16x16x32_bf16(a, ffB[ks], cB, 0, 0, 0);
        }
        // output: 4 consecutive cols = ch0 + n*16 + lg*4 + 0..3
        int col0 = ch0 + n * 16 + lg * 4;
        int rr = col0 >> 6;
        int oo = col0 & 63;
        if (rowA < NDRUG) {
            ushort4 pk;
            pk.x = f2bf(cA[0] * cjvA);
            pk.y = f2bf(cA[1] * cjvA);
            pk.z = f2bf(cA[2] * cjvA);
            pk.w = f2bf(cA[3] * cjvA);
            *(ushort4*)&g[((size_t)rr * NROWP + rowA) * OUTD + oo] = pk;
        }
        if (rowB < NDRUG) {
            ushort4 pk;
            pk.x = f2bf(cB[0] * cjvB);
            pk.y = f2bf(cB[1] * cjvB);
            pk.z = f2bf(cB[2] * cjvB);
            pk.w = f2bf(cB[3] * cjvB);
            *(ushort4*)&g[((size_t)rr * NROWP + rowB) * OUTD + oo] = pk;
        }
    }
}

// ---------------------------------------------------------------------------
// Pass 2 (merged fine-sort + aggregation): one block per coarse bucket.
// Wave-level scan (2 barriers); quarter-per-bin aggregation with 4-deep
// unrolled serial loop. XCD-contiguous bucket remap.
// ---------------------------------------------------------------------------
__global__ __launch_bounds__(256, 8) void k_fuse(const ushort_t* __restrict__ gd,
                                                 const ushort_t* __restrict__ gi,
                                                 const int* __restrict__ tails,
                                                 const uint_t* __restrict__ coarse,
                                                 const float* __restrict__ ci_drug,
                                                 const float* __restrict__ ci_dis,
                                                 const float* __restrict__ fcb,
                                                 float* __restrict__ out_drug,
                                                 float* __restrict__ out_dis) {
    int bid = blockIdx.x;
    int gb = (bid & 7) * (NGB / 8) + (bid >> 3);   // XCD-contiguous range
    int dir = gb / (RR * NBKT);
    int rem = gb - dir * (RR * NBKT);
    int r = rem / NBKT;
    int b = rem - r * NBKT;

    const ushort_t* g = dir ? gi : gd;
    const float* ci   = dir ? ci_drug : ci_dis;
    float* outp       = dir ? out_drug : out_dis;

    const uint_t* cb = coarse + (size_t)gb * CAP;
    int count = tails[gb]; if (count > CAP) count = CAP;

    __shared__ ushort_t lsorted[CAP];   // 8 KB
    __shared__ int hist[256];
    __shared__ int incl[256];           // inclusive scan
    __shared__ int cur[256];
    __shared__ int wsum[4];

    int t = threadIdx.x;
    const int w    = t >> 6;
    const int lane = t & 63;

    // register-stage the bucket: one NT read of coarse (uniform skip)
    uint_t ereg[16];
#pragma unroll
    for (int k = 0; k < 16; ++k) {
        if (k * 256 < count) {
            int i = k * 256 + t;
            ereg[k] = (i < count) ? __builtin_nontemporal_load(cb + i) : 0xFFFFFFFFu;
        } else {
            ereg[k] = 0xFFFFFFFFu;
        }
    }

    hist[t] = 0;
    __syncthreads();
#pragma unroll
    for (int k = 0; k < 16; ++k) {
        if (k * 256 < count) {
            if (ereg[k] != 0xFFFFFFFFu)
                atomicAdd(&hist[(ereg[k] >> 16) & 255], 1);
        }
    }
    __syncthreads();

    // wave-level inclusive scan of hist across the 256 threads
    int v = hist[t];
    int x = v;
#pragma unroll
    for (int off = 1; off < 64; off <<= 1) {
        int y = __shfl_up(x, off);
        if (lane >= off) x += y;
    }
    if (lane == 63) wsum[w] = x;
    __syncthreads();
    int base = 0;
#pragma unroll
    for (int i = 0; i < 4; ++i)
        if (i < w) base += wsum[i];
    int inc = x + base;
    incl[t] = inc;
    cur[t] = inc - v;                  // exclusive start
    __syncthreads();

#pragma unroll
    for (int k = 0; k < 16; ++k) {
        if (k * 256 < count) {
            uint_t e = ereg[k];
            if (e != 0xFFFFFFFFu) {
                int pos = atomicAdd(&cur[(e >> 16) & 255], 1);
                if (pos < CAP) lsorted[pos] = (ushort_t)e;
            }
        }
    }
    __syncthreads();

    // aggregation: wave w -> bins w*64..w*64+63, 4 at a time (1 per quarter)
    const int quarter = lane >> 4;
    const int q       = lane & 15;
    const ushort_t* grow = g + (size_t)r * NROWP * OUTD + q * 4;
    const float4 bb = *(const float4*)(fcb + q * 4);

    for (int ib = 0; ib < 16; ++ib) {
        int dstlow = w * 64 + ib * 4 + quarter;   // this quarter's bin
        int dst = b * 256 + dstlow;
        int start = dstlow ? incl[dstlow - 1] : 0;
        int end   = incl[dstlow];
        int len   = end - start;
        int lenm1 = len > 0 ? len - 1 : 0;
        if (start > CAP - 1) start = CAP - 1;     // empty-tail guard

        // loop bound = max over the 4 quarters in this wave
        int wm = len;
        wm = max(wm, __shfl_xor(wm, 16));
        wm = max(wm, __shfl_xor(wm, 32));

        f32x2 a01 = {0.f, 0.f}, a23 = {0.f, 0.f};
        for (int s = 0; s < wm; s += 4) {
            uint2 u[4];
#pragma unroll
            for (int k2 = 0; k2 < 4; ++k2) {
                int ss = s + k2;
                int so = ss < lenm1 ? ss : lenm1;
                int sj = (int)lsorted[start + so];
                u[k2] = *(const uint2*)(grow + (size_t)sj * OUTD);
            }
#pragma unroll
            for (int k2 = 0; k2 < 4; ++k2) {
                int ss = s + k2;
                bool act = ss < len;
                uint_t ux = act ? u[k2].x : 0u;
                uint_t uy = act ? u[k2].y : 0u;
                f32x2 p0 = { __uint_as_float(ux << 16), __uint_as_float(ux & 0xffff0000u) };
                f32x2 p1 = { __uint_as_float(uy << 16), __uint_as_float(uy & 0xffff0000u) };
                a01 += p0;
                a23 += p1;
            }
        }
        if (dst < NDIS) {
            float civ = ci[dst];
            f32x4 o;
            o.x = a01.x * civ + bb.x;
            o.y = a01.y * civ + bb.y;
            o.z = a23.x * civ + bb.z;
            o.w = a23.y * civ + bb.w;
            __builtin_nontemporal_store(o,
                (f32x4*)(outp + (size_t)dst * NCOL + r * OUTD + q * 4));
        }
    }
}

// ---------------------------------------------------------------------------
extern "C" void kernel_launch(void* const* d_in, const int* in_sizes, int n_in,
                              void* d_out, int out_size, void* d_ws, size_t ws_size,
                              hipStream_t stream) {
    const float* drug_feat = (const float*)d_in[0];
    const float* dis_feat  = (const float*)d_in[1];
    const float* cj_drug   = (const float*)d_in[2];
    const float* ci_drug   = (const float*)d_in[3];
    const float* cj_dis    = (const float*)d_in[4];
    const float* ci_dis    = (const float*)d_in[5];
    const float* att       = (const float*)d_in[6];
    const float* basis     = (const float*)d_in[7];
    const float* fcw       = (const float*)d_in[8];
    const float* fcb       = (const float*)d_in[9];
    const int*   edge_drug = (const int*)d_in[10];
    const int*   edge_dis  = (const int*)d_in[11];

    float* out      = (float*)d_out;
    float* out_drug = out;
    float* out_dis  = out + (size_t)NDRUG * NCOL;

    // Workspace layout (~96.3 MB):
    //   gd (bf16, [R][50016][64])  32,010,240 @ 0
    //   gi (bf16, [R][50016][64])  32,010,240 @ 32,010,240
    //   Mt (bf16)          163,840 @ 64,020,480
    //   tails (int)          7,840 @ 64,184,320
    //   coarse (u32)    32,112,640 @ 64,192,160
    char* ws = (char*)d_ws;
    ushort_t* gd      = (ushort_t*)ws;
    ushort_t* gi      = (ushort_t*)(ws + 32010240);
    ushort_t* Mtb     = (ushort_t*)(ws + 64020480);
    int*      tails   = (int*)(ws + 64184320);
    uint_t*   coarse  = (uint_t*)(ws + 64192160);

    // zero bucket tails
    hipMemsetAsync(tails, 0, NGB * sizeof(int), stream);

    // A: fused att*basis*fc_w -> Mt bf16 [320][128]
    k_make_M<<<dim3((RR * FF * OUTD + 255) / 256), 256, 0, stream>>>(att, basis, fcw, Mtb);

    // Merged: coarse partition + pad-row zeroing + MFMA transform
    k_pg<<<dim3(PG_BLOCKS), 256, 0, stream>>>(edge_drug, edge_dis, tails, coarse,
                                              drug_feat, cj_drug, dis_feat, cj_dis,
                                              Mtb, gd, gi);

    // Merged fine-sort + quarter-per-bin aggregation + fused ci-scale + bias
    k_fuse<<<dim3(NGB), 256, 0, stream>>>(gd, gi, tails, coarse,
                                          ci_drug, ci_dis, fcb,
                                          out_drug, out_dis);
}